// Round 2
// 713.407 us; speedup vs baseline: 1.0360x; 1.0360x over previous
//
#include <hip/hip_runtime.h>

#define RNN_B 256
#define RNN_T 2048
#define RNN_IN 64
#define RNN_N 32
#define RNN_O 32
#define RNN_R 6
#define RNN_ALPHA 0.1f
#define KSCALE 2.8853900817779268f   /* 2*log2(e): folded into cM and xp */

// ---------------------------------------------------------------------------
// Kernel 1: xp[b][t][n] = KSCALE * (bias[n] + sum_i W_in[n][i] * u[b][t][i])
// KSCALE is folded here so k_recur's z-chain starts directly from xp.
// ---------------------------------------------------------------------------
__global__ __launch_bounds__(256) void k_xproj(
    const float* __restrict__ u, const float* __restrict__ W_in,
    const float* __restrict__ bias, float* __restrict__ xp)
{
    const int tid = blockIdx.x * 256 + threadIdx.x;   // = b*T + t
    const float4* __restrict__ u4 =
        reinterpret_cast<const float4*>(u) + (size_t)tid * (RNN_IN / 4);
    float acc[RNN_N];
    #pragma unroll
    for (int n = 0; n < RNN_N; ++n) acc[n] = bias[n];
    #pragma unroll
    for (int q = 0; q < RNN_IN / 4; ++q) {
        const float4 v = u4[q];
        #pragma unroll
        for (int n = 0; n < RNN_N; ++n) {
            const float* wr = W_in + n * RNN_IN + 4 * q;   // uniform -> s_load
            acc[n] = fmaf(wr[0], v.x, acc[n]);
            acc[n] = fmaf(wr[1], v.y, acc[n]);
            acc[n] = fmaf(wr[2], v.z, acc[n]);
            acc[n] = fmaf(wr[3], v.w, acc[n]);
        }
    }
    float4* __restrict__ o4 =
        reinterpret_cast<float4*>(xp) + (size_t)tid * (RNN_N / 4);
    #pragma unroll
    for (int q = 0; q < RNN_N / 4; ++q)
        o4[q] = make_float4(KSCALE * acc[4*q+0], KSCALE * acc[4*q+1],
                            KSCALE * acc[4*q+2], KSCALE * acc[4*q+3]);
}

// ---------------------------------------------------------------------------
// Row-local (16-lane) all-reduce: pure VALU DPP, no LDS pipe, no readlane.
// ---------------------------------------------------------------------------
template <int CTRL>
__device__ __forceinline__ float dpp_add(float v) {
    int t = __builtin_amdgcn_update_dpp(0, __float_as_int(v), CTRL, 0xf, 0xf, true);
    return v + __int_as_float(t);
}
__device__ __forceinline__ float sum16(float v) {
    v = dpp_add<0xB1>(v);    // quad_perm [1,0,3,2] : xor1
    v = dpp_add<0x4E>(v);    // quad_perm [2,3,0,1] : xor2
    v = dpp_add<0x141>(v);   // row_half_mirror     : cross-quad within 8
    v = dpp_add<0x140>(v);   // row_mirror          : cross-8 within 16
    return v;
}

__device__ __forceinline__ float fast_exp2(float x) {
#if __has_builtin(__builtin_amdgcn_exp2f)
    return __builtin_amdgcn_exp2f(x);
#else
    return __expf(x * 0.6931471805599453f);
#endif
}
__device__ __forceinline__ float fast_rcp(float x) {
#if __has_builtin(__builtin_amdgcn_rcpf)
    return __builtin_amdgcn_rcpf(x);
#else
    return __frcp_rn(x);
#endif
}

// ---------------------------------------------------------------------------
// Kernel 2: sequential scan, one wave per batch. Lane holds the ADJACENT pair
// (hA=h[2k], hB=h[2k+1]), k=lane&15; all four 16-rows replicate. Per step,
// per rank r: fold the pair locally (mul+fma), then 4 row-local DPP adds ->
// every lane holds S_r in a VGPR.
//   h' = (0.9h + 0.1) - 0.2 * rcp(exp2(z) + 1),  z = xp + sum_r cM[r]*S_r
// (xp and cM carry the 2*log2e prescale.)
// Memory: xp read from a DIFFERENT restrict buffer than the h store target
// (ws), so the compiler needs no store->load ordering waits; PF=8 float2
// prefetch ring gives ~8 steps (>1500 cyc) of latency slack vs ~900 cyc HBM.
// ---------------------------------------------------------------------------
__global__ __launch_bounds__(64, 1) void k_recur(
    const float* __restrict__ m, const float* __restrict__ nvec,
    const float* __restrict__ Mmat, const float* __restrict__ Nmat,
    const float* __restrict__ xp,    // [B,T,N] prescaled input projections
    float* __restrict__ hout,        // [B,T,N] hidden states (ws or out)
    float* __restrict__ hfin)
{
    const int b    = blockIdx.x;
    const int lane = threadIdx.x;
    const int k    = lane & 15;          // pair (2k, 2k+1)
    const int iA   = 2 * k;
    const int iB   = 2 * k + 1;

    // Right factors (pre-reduction), both halves of the pair:
    float cNA[RNN_R + 1], cNB[RNN_R + 1];
    cNA[0] = nvec[iA];  cNB[0] = nvec[iB];
    #pragma unroll
    for (int r = 0; r < RNN_R; ++r) {
        cNA[r+1] = Nmat[iA*RNN_R + r];
        cNB[r+1] = Nmat[iB*RNN_R + r];
    }
    // Left factors (post-reduction), prescaled by 2*log2(e):
    float cMA[RNN_R + 1], cMB[RNN_R + 1];
    cMA[0] = KSCALE * m[iA];  cMB[0] = KSCALE * m[iB];
    #pragma unroll
    for (int r = 0; r < RNN_R; ++r) {
        cMA[r+1] = KSCALE * Mmat[iA*RNN_R + r];
        cMB[r+1] = KSCALE * Mmat[iB*RNN_R + r];
    }

    const float2* __restrict__ x2 =
        reinterpret_cast<const float2*>(xp + (size_t)b * (RNN_T * RNN_N)) + k;
    float2* __restrict__ h2 =
        reinterpret_cast<float2*>(hout + (size_t)b * (RNN_T * RNN_N));

    float hA = 0.0f, hB = 0.0f;

    const int PF = 8;                    // prefetch ring (float2/step)
    float2 xr[PF];
    #pragma unroll
    for (int i = 0; i < PF; ++i) xr[i] = x2[i * (RNN_N / 2)];

    #pragma unroll 8
    for (int t = 0; t < RNN_T; ++t) {
        const float xA = xr[0].x, xB = xr[0].y;
        #pragma unroll
        for (int i = 0; i < PF - 1; ++i) xr[i] = xr[i + 1];
        // Unconditional prefetch (reads past T land in allocated space; unused).
        xr[PF - 1] = x2[(t + PF) * (RNN_N / 2)];

        // 7 reductions: local pair-fold + 4 DPP stages, all-VALU.
        float s[RNN_R + 1];
        #pragma unroll
        for (int r = 0; r < RNN_R + 1; ++r)
            s[r] = sum16(fmaf(hB, cNB[r], hA * cNA[r]));

        // z = xp + sum_r cM[r]*s[r]; two chains each (xp already prescaled).
        float zA0 = fmaf(cMA[0], s[0], xA);
        float zB0 = fmaf(cMB[0], s[0], xB);
        float zA1 = cMA[1] * s[1];
        float zB1 = cMB[1] * s[1];
        zA0 = fmaf(cMA[2], s[2], zA0);  zB0 = fmaf(cMB[2], s[2], zB0);
        zA1 = fmaf(cMA[3], s[3], zA1);  zB1 = fmaf(cMB[3], s[3], zB1);
        zA0 = fmaf(cMA[4], s[4], zA0);  zB0 = fmaf(cMB[4], s[4], zB0);
        zA1 = fmaf(cMA[5], s[5], zA1);  zB1 = fmaf(cMB[5], s[5], zB1);
        zA0 = fmaf(cMA[6], s[6], zA0);  zB0 = fmaf(cMB[6], s[6], zB0);
        const float zA = zA0 + zA1, zB = zB0 + zB1;

        // tanh via exp2: h' = (0.9h + 0.1) - 0.2*rcp(exp2(z)+1)
        const float eA = fast_exp2(zA), eB = fast_exp2(zB);
        const float gA = fmaf(1.0f - RNN_ALPHA, hA, RNN_ALPHA);
        const float gB = fmaf(1.0f - RNN_ALPHA, hB, RNN_ALPHA);
        hA = fmaf(-2.0f * RNN_ALPHA, fast_rcp(eA + 1.0f), gA);
        hB = fmaf(-2.0f * RNN_ALPHA, fast_rcp(eB + 1.0f), gB);

        // Lanes 0..15 hold the full h as adjacent pairs: one coalesced
        // 128B float2 store per step.
        if (lane < 16) h2[t * (RNN_N / 2) + lane] = make_float2(hA, hB);
    }
    if (lane < 16)
        reinterpret_cast<float2*>(hfin + (size_t)b * RNN_N)[lane] =
            make_float2(hA, hB);
}

// ---------------------------------------------------------------------------
// Kernel 3: output projection, separate src (h) / dst (y) streams.
// Falls back to in-place when hsrc == ydst (no-ws mode): all loads feed every
// y[o], so data dependence keeps stores after loads.
// ---------------------------------------------------------------------------
__global__ __launch_bounds__(256) void k_out(
    const float* __restrict__ W_out, const float* __restrict__ b_out,
    const float* __restrict__ hsrc, float* __restrict__ ydst)
{
    const int tid = blockIdx.x * 256 + threadIdx.x;   // = b*T + t
    const float4* __restrict__ p4 =
        reinterpret_cast<const float4*>(hsrc) + (size_t)tid * (RNN_N / 4);
    float4* __restrict__ q4 =
        reinterpret_cast<float4*>(ydst) + (size_t)tid * (RNN_N / 4);
    float y[RNN_O];
    #pragma unroll
    for (int o = 0; o < RNN_O; ++o) y[o] = b_out[o];
    #pragma unroll
    for (int q = 0; q < RNN_N / 4; ++q) {
        const float4 v = p4[q];
        #pragma unroll
        for (int o = 0; o < RNN_O; ++o) {
            const float* wr = W_out + o * RNN_N + 4 * q;  // uniform -> s_load
            y[o] = fmaf(wr[0], v.x, y[o]);
            y[o] = fmaf(wr[1], v.y, y[o]);
            y[o] = fmaf(wr[2], v.z, y[o]);
            y[o] = fmaf(wr[3], v.w, y[o]);
        }
    }
    #pragma unroll
    for (int q = 0; q < RNN_N / 4; ++q)
        q4[q] = make_float4(y[4*q+0], y[4*q+1], y[4*q+2], y[4*q+3]);
}

extern "C" void kernel_launch(void* const* d_in, const int* in_sizes, int n_in,
                              void* d_out, int out_size, void* d_ws, size_t ws_size,
                              hipStream_t stream)
{
    const float* u     = (const float*)d_in[0];  // [256,2048,64]
    const float* W_in  = (const float*)d_in[1];  // [32,64]
    const float* m     = (const float*)d_in[2];  // [32,1]
    const float* nvec  = (const float*)d_in[3];  // [32,1]
    const float* Mmat  = (const float*)d_in[4];  // [32,6]
    const float* Nmat  = (const float*)d_in[5];  // [32,6]
    const float* bias  = (const float*)d_in[6];  // [32]
    const float* W_out = (const float*)d_in[7];  // [32,32]
    const float* b_out = (const float*)d_in[8];  // [32]
    float* out = (float*)d_out;                  // outputs [256,2048,32] ++ h_final [256,32]

    float* hfin = out + (size_t)RNN_B * RNN_T * RNN_N;

    // h states routed through the workspace so k_recur's loads (xp, from out)
    // and stores (h, to ws) are provably non-aliasing. Fallback: in-place.
    const size_t hbytes = (size_t)RNN_B * RNN_T * RNN_N * sizeof(float);
    float* hbuf = (ws_size >= hbytes) ? (float*)d_ws : out;

    k_xproj<<<(RNN_B * RNN_T) / 256, 256, 0, stream>>>(u, W_in, bias, out);
    k_recur<<<RNN_B, 64, 0, stream>>>(m, nvec, Mmat, Nmat, out, hbuf, hfin);
    k_out  <<<(RNN_B * RNN_T) / 256, 256, 0, stream>>>(W_out, b_out, hbuf, out);
}

// Round 3
// 608.428 us; speedup vs baseline: 1.2147x; 1.1725x over previous
//
#include <hip/hip_runtime.h>

#define RNN_B 256
#define RNN_T 2048
#define RNN_IN 64
#define RNN_N 32
#define RNN_O 32
#define RNN_R 6
#define RNN_ALPHA 0.1f
#define KSCALE 2.8853900817779268f   /* 2*log2(e): folded into cM and xp */

// ---------------------------------------------------------------------------
// Kernel 1: xp[b][t][n] = KSCALE * (bias[n] + sum_i W_in[n][i] * u[b][t][i])
// ---------------------------------------------------------------------------
__global__ __launch_bounds__(256) void k_xproj(
    const float* __restrict__ u, const float* __restrict__ W_in,
    const float* __restrict__ bias, float* __restrict__ xp)
{
    const int tid = blockIdx.x * 256 + threadIdx.x;   // = b*T + t
    const float4* __restrict__ u4 =
        reinterpret_cast<const float4*>(u) + (size_t)tid * (RNN_IN / 4);
    float acc[RNN_N];
    #pragma unroll
    for (int n = 0; n < RNN_N; ++n) acc[n] = bias[n];
    #pragma unroll
    for (int q = 0; q < RNN_IN / 4; ++q) {
        const float4 v = u4[q];
        #pragma unroll
        for (int n = 0; n < RNN_N; ++n) {
            const float* wr = W_in + n * RNN_IN + 4 * q;   // uniform -> s_load
            acc[n] = fmaf(wr[0], v.x, acc[n]);
            acc[n] = fmaf(wr[1], v.y, acc[n]);
            acc[n] = fmaf(wr[2], v.z, acc[n]);
            acc[n] = fmaf(wr[3], v.w, acc[n]);
        }
    }
    float4* __restrict__ o4 =
        reinterpret_cast<float4*>(xp) + (size_t)tid * (RNN_N / 4);
    #pragma unroll
    for (int q = 0; q < RNN_N / 4; ++q)
        o4[q] = make_float4(KSCALE * acc[4*q+0], KSCALE * acc[4*q+1],
                            KSCALE * acc[4*q+2], KSCALE * acc[4*q+3]);
}

// ---------------------------------------------------------------------------
// Row-local (16-lane) all-reduce stages: pure VALU DPP.
// ---------------------------------------------------------------------------
template <int CTRL>
__device__ __forceinline__ float dpp_add(float v) {
    int t = __builtin_amdgcn_update_dpp(0, __float_as_int(v), CTRL, 0xf, 0xf, true);
    return v + __int_as_float(t);
}

// Cross-half (lane ^ 32) pairwise sum in ALL lanes: one v_permlane32_swap
// (both results used) + one add. Orientation of the swap doesn't matter:
// r.x + r.y == v[i] + v[i^32] either way. Fallback: shfl (ds_bpermute).
__device__ __forceinline__ float xhalf_sum(float v) {
#if __has_builtin(__builtin_amdgcn_permlane32_swap)
    typedef int v2i __attribute__((ext_vector_type(2)));
    v2i r = __builtin_amdgcn_permlane32_swap(__float_as_int(v),
                                             __float_as_int(v), false, false);
    return __int_as_float(r.x) + __int_as_float(r.y);
#else
    return v + __shfl_xor(v, 32, 64);
#endif
}

__device__ __forceinline__ float fast_exp2(float x) {
#if __has_builtin(__builtin_amdgcn_exp2f)
    return __builtin_amdgcn_exp2f(x);
#else
    return __expf(x * 0.6931471805599453f);
#endif
}
__device__ __forceinline__ float fast_rcp(float x) {
#if __has_builtin(__builtin_amdgcn_rcpf)
    return __builtin_amdgcn_rcpf(x);
#else
    return __frcp_rn(x);
#endif
}

// ---------------------------------------------------------------------------
// Kernel 2: sequential scan, one wave per batch.
// Lane layout: k = lane&15 owns the adjacent pair (hA=h[2k], hB=h[2k+1]);
// all four 16-rows hold identical replicated state.
// RANK SPLIT across wave halves: lanes <32 compute rank-sums for ranks 0..3
// (rank 0 = m n^T, ranks 1..6 = M N^T cols), lanes >=32 compute ranks 4..6
// plus a zero pad. Each half needs only FOUR 16-lane DPP reductions per step
// (vs 7 before), written stage-outer so the 4 chains interleave. Each half
// folds its ranks (+x in half 0 via mask) into a partial z; one
// v_permlane32_swap + add combines the halves in every lane. All-VALU.
//   h' = (0.9h + 0.1) - 0.2 * rcp(exp2(z) + 1),  z prescaled by 2*log2(e).
// ---------------------------------------------------------------------------
__global__ __launch_bounds__(64, 1) void k_recur(
    const float* __restrict__ m, const float* __restrict__ nvec,
    const float* __restrict__ Mmat, const float* __restrict__ Nmat,
    const float* __restrict__ xp,    // [B,T,N] prescaled input projections
    float* __restrict__ hout,        // [B,T,N] hidden states (ws or out)
    float* __restrict__ hfin)
{
    const int b    = blockIdx.x;
    const int lane = threadIdx.x;
    const int k    = lane & 15;          // pair (2k, 2k+1)
    const int iA   = 2 * k;
    const int iB   = 2 * k + 1;
    const int half = (lane >> 5) & 1;    // 0: ranks 0..3 (+x), 1: ranks 4..6

    // Per-lane coefficients for this half's 4 rank slots.
    // Slot j handles global rank r = 4*half + j; r==0 -> m/n, 1..6 -> col r-1,
    // r==7 -> zero pad.
    float cnA[4], cnB[4], cmA[4], cmB[4];
    #pragma unroll
    for (int j = 0; j < 4; ++j) {
        const int r = 4 * half + j;
        if (r == 0) {
            cnA[j] = nvec[iA];              cnB[j] = nvec[iB];
            cmA[j] = KSCALE * m[iA];        cmB[j] = KSCALE * m[iB];
        } else if (r <= RNN_R) {
            cnA[j] = Nmat[iA*RNN_R + (r-1)];          cnB[j] = Nmat[iB*RNN_R + (r-1)];
            cmA[j] = KSCALE * Mmat[iA*RNN_R + (r-1)]; cmB[j] = KSCALE * Mmat[iB*RNN_R + (r-1)];
        } else {
            cnA[j] = 0.f; cnB[j] = 0.f; cmA[j] = 0.f; cmB[j] = 0.f;
        }
    }
    const float xmask = (half == 0) ? 1.0f : 0.0f;   // x enters via half 0 only

    const float2* __restrict__ x2 =
        reinterpret_cast<const float2*>(xp + (size_t)b * (RNN_T * RNN_N)) + k;
    float2* __restrict__ h2 =
        reinterpret_cast<float2*>(hout + (size_t)b * (RNN_T * RNN_N));

    float hA = 0.0f, hB = 0.0f;

    const int PF = 8;                    // prefetch ring (one float2/step)
    float2 xr[PF];
    #pragma unroll
    for (int i = 0; i < PF; ++i) xr[i] = x2[i * (RNN_N / 2)];

    #pragma unroll 8
    for (int t = 0; t < RNN_T; ++t) {
        const float xA = xr[0].x, xB = xr[0].y;
        #pragma unroll
        for (int i = 0; i < PF - 1; ++i) xr[i] = xr[i + 1];
        // Unconditional prefetch (reads past T stay inside the allocation).
        xr[PF - 1] = x2[(t + PF) * (RNN_N / 2)];

        // 4 rank-sums per half: local pair-fold, then 4 DPP stages written
        // STAGE-OUTER so the four dependency chains interleave.
        float s0 = fmaf(hB, cnB[0], hA * cnA[0]);
        float s1 = fmaf(hB, cnB[1], hA * cnA[1]);
        float s2 = fmaf(hB, cnB[2], hA * cnA[2]);
        float s3 = fmaf(hB, cnB[3], hA * cnA[3]);
        s0 = dpp_add<0xB1>(s0);  s1 = dpp_add<0xB1>(s1);
        s2 = dpp_add<0xB1>(s2);  s3 = dpp_add<0xB1>(s3);   // xor1
        s0 = dpp_add<0x4E>(s0);  s1 = dpp_add<0x4E>(s1);
        s2 = dpp_add<0x4E>(s2);  s3 = dpp_add<0x4E>(s3);   // xor2
        s0 = dpp_add<0x141>(s0); s1 = dpp_add<0x141>(s1);
        s2 = dpp_add<0x141>(s2); s3 = dpp_add<0x141>(s3);  // half-mirror
        s0 = dpp_add<0x140>(s0); s1 = dpp_add<0x140>(s1);
        s2 = dpp_add<0x140>(s2); s3 = dpp_add<0x140>(s3);  // mirror

        // Partial z for this half (x masked into half 0), then cross-half sum.
        float tA = fmaf(cmA[0], s0, fmaf(cmA[1], s1, xA * xmask));
        float tB = fmaf(cmB[0], s0, fmaf(cmB[1], s1, xB * xmask));
        float uA = fmaf(cmA[2], s2, cmA[3] * s3);
        float uB = fmaf(cmB[2], s2, cmB[3] * s3);
        const float zA = xhalf_sum(tA + uA);
        const float zB = xhalf_sum(tB + uB);

        // tanh via exp2: h' = (0.9h + 0.1) - 0.2*rcp(exp2(z)+1)
        const float eA = fast_exp2(zA), eB = fast_exp2(zB);
        const float gA = fmaf(1.0f - RNN_ALPHA, hA, RNN_ALPHA);
        const float gB = fmaf(1.0f - RNN_ALPHA, hB, RNN_ALPHA);
        hA = fmaf(-2.0f * RNN_ALPHA, fast_rcp(eA + 1.0f), gA);
        hB = fmaf(-2.0f * RNN_ALPHA, fast_rcp(eB + 1.0f), gB);

        // Lanes 0..15 store the full h vector as adjacent pairs: one
        // coalesced 128B float2 store per step.
        if (lane < 16) h2[t * (RNN_N / 2) + lane] = make_float2(hA, hB);
    }
    if (lane < 16)
        reinterpret_cast<float2*>(hfin + (size_t)b * RNN_N)[lane] =
            make_float2(hA, hB);
}

// ---------------------------------------------------------------------------
// Kernel 3: output projection, separate src (h) / dst (y) streams.
// ---------------------------------------------------------------------------
__global__ __launch_bounds__(256) void k_out(
    const float* __restrict__ W_out, const float* __restrict__ b_out,
    const float* __restrict__ hsrc, float* __restrict__ ydst)
{
    const int tid = blockIdx.x * 256 + threadIdx.x;   // = b*T + t
    const float4* __restrict__ p4 =
        reinterpret_cast<const float4*>(hsrc) + (size_t)tid * (RNN_N / 4);
    float4* __restrict__ q4 =
        reinterpret_cast<float4*>(ydst) + (size_t)tid * (RNN_N / 4);
    float y[RNN_O];
    #pragma unroll
    for (int o = 0; o < RNN_O; ++o) y[o] = b_out[o];
    #pragma unroll
    for (int q = 0; q < RNN_N / 4; ++q) {
        const float4 v = p4[q];
        #pragma unroll
        for (int o = 0; o < RNN_O; ++o) {
            const float* wr = W_out + o * RNN_N + 4 * q;  // uniform -> s_load
            y[o] = fmaf(wr[0], v.x, y[o]);
            y[o] = fmaf(wr[1], v.y, y[o]);
            y[o] = fmaf(wr[2], v.z, y[o]);
            y[o] = fmaf(wr[3], v.w, y[o]);
        }
    }
    #pragma unroll
    for (int q = 0; q < RNN_N / 4; ++q)
        q4[q] = make_float4(y[4*q+0], y[4*q+1], y[4*q+2], y[4*q+3]);
}

extern "C" void kernel_launch(void* const* d_in, const int* in_sizes, int n_in,
                              void* d_out, int out_size, void* d_ws, size_t ws_size,
                              hipStream_t stream)
{
    const float* u     = (const float*)d_in[0];  // [256,2048,64]
    const float* W_in  = (const float*)d_in[1];  // [32,64]
    const float* m     = (const float*)d_in[2];  // [32,1]
    const float* nvec  = (const float*)d_in[3];  // [32,1]
    const float* Mmat  = (const float*)d_in[4];  // [32,6]
    const float* Nmat  = (const float*)d_in[5];  // [32,6]
    const float* bias  = (const float*)d_in[6];  // [32]
    const float* W_out = (const float*)d_in[7];  // [32,32]
    const float* b_out = (const float*)d_in[8];  // [32]
    float* out = (float*)d_out;                  // outputs [256,2048,32] ++ h_final [256,32]

    float* hfin = out + (size_t)RNN_B * RNN_T * RNN_N;

    // h states routed through the workspace so k_recur's loads (xp, from out)
    // and stores (h, to ws) are provably non-aliasing. Fallback: in-place.
    const size_t hbytes = (size_t)RNN_B * RNN_T * RNN_N * sizeof(float);
    float* hbuf = (ws_size >= hbytes) ? (float*)d_ws : out;

    k_xproj<<<(RNN_B * RNN_T) / 256, 256, 0, stream>>>(u, W_in, bias, out);
    k_recur<<<RNN_B, 64, 0, stream>>>(m, nvec, Mmat, Nmat, out, hbuf, hfin);
    k_out  <<<(RNN_B * RNN_T) / 256, 256, 0, stream>>>(W_out, b_out, hbuf, out);
}